// Round 11
// baseline (235.572 us; speedup 1.0000x reference)
//
#include <hip/hip_runtime.h>
#include <math.h>

#define KB 16

// Native clang vector type — required for __builtin_nontemporal_load/store.
typedef float vf4 __attribute__((ext_vector_type(4)));

// Per-element core, x16-domain fold (ROUND 11, bit-exact vs prior rounds):
//   t16 = |x| * (16*rcpa)       == 16 * (|x|*rcpa)        [exact pow2 scale]
//   sub = t16 - floor(jf)       == 16 * (xt - dst[j])     [both operands 16x,
//                                                          fp sub scales exactly]
//   y   = gamma16 * sub + beta  where gamma16 = gamma/16  [exact pow2 scale]
//       == round(gamma * (xt-dst[j])) + beta              [same real product,
//                                                          same rounding]
// so y, m, and the output are bit-identical to R4-R10 (absmax 0.0), with two
// fewer fmul per element. Table holds pv[m] = alpha*zval[m] (bit-exact fold,
// R4-R10) and (gamma16, beta) pairs.
__device__ __forceinline__ float lcq_core(float xv, float alpha, float rcpa16,
                                          const float2* s_gb,
                                          const float* s_pv)
{
    float a   = fabsf(xv);
    float t16 = __fmul_rn(a, rcpa16);               // 16 * x_tmp
    float jf  = fminf(t16, 15.0f);
    int   j   = (int)jf;                            // searchsorted(dst,·,right)-1
    float2 gb = s_gb[j];                            // (gamma/16, beta), ds_read_b64
    float fj  = floorf(jf);                         // == (float)j
    float y   = __fadd_rn(__fmul_rn(gb.x, __fsub_rn(t16, fj)), gb.y);
    float t   = rintf(__fmul_rn(y, 15.0f));         // m = round(y*s), half-even; t>=0
    int   m   = (int)fminf(t, 15.0f);
    float r   = (a < alpha) ? s_pv[m] : alpha;      // flag select, alpha pre-folded
    return copysignf(r, xv);                        // x==0 -> 0 (pv[0]==0)
}

// ROUND 11: champion structure (R10: NT/NT, 8 loads in flight, per-wave LDS
// tables, barrier-free) + 2-iteration unrolled loop per block. Mechanism:
// one-shot waves pay a store-drain tail (vmcnt(0) before s_endpgm, ~900cy of
// a ~2700cy life) plus per-block dispatch + table build; looping twice in the
// SAME wave halves all three while REUSING the same 8 vf4 registers — stays
// in the <=64-VGPR/32-wave tier that R9 proved critical (16 live vf4 = 68
// VGPR = occupancy collapse). Iter-2 loads issue right after iter-1 stores
// (fire-and-forget), so compute/memory duty cycle matches block churn minus
// dispatch gaps. MLP stays 8 (R8-proven optimum).
__global__ __launch_bounds__(256) void lcq_kernel(
    const float* __restrict__ x,
    const float* __restrict__ thr,
    const float* __restrict__ theta,
    float* __restrict__ out,
    long long n)
{
    __shared__ float s_tab[4][64];  // per-wave slot: [0..31] (g16,b) x16, [32..47] pv

    const long long n4ll = n >> 2;
    const vf4* __restrict__ x4 = (const vf4*)x;
    vf4* __restrict__ o4 = (vf4*)out;

    // ---- (0) uniform inputs first: SMEM path (lgkmcnt), independent of the
    //          NT data loads' vmcnt ----
    float th[KB];
    #pragma unroll
    for (int i = 0; i < KB; ++i) th[i] = theta[i];
    const float alpha  = thr[0];
    const float rcpa   = __fdiv_rn(1.0f, alpha);    // exact for pow2 alpha (bench: 1.0)
    const float rcpa16 = __fmul_rn(rcpa, 16.0f);    // exact pow2 scale

    const unsigned base = blockIdx.x * 4096u + threadIdx.x;  // float4 index

    // ---- (1) issue iteration-1's 8 NT loads ASAP ----
    const bool full0 = ((long long)blockIdx.x * 4096ll + 2048ll <= n4ll);
    vf4 v0, v1, v2, v3, v4, v5, v6, v7;
    if (full0) {
        v0 = __builtin_nontemporal_load(&x4[base]);
        v1 = __builtin_nontemporal_load(&x4[base +  256u]);
        v2 = __builtin_nontemporal_load(&x4[base +  512u]);
        v3 = __builtin_nontemporal_load(&x4[base +  768u]);
        v4 = __builtin_nontemporal_load(&x4[base + 1024u]);
        v5 = __builtin_nontemporal_load(&x4[base + 1280u]);
        v6 = __builtin_nontemporal_load(&x4[base + 1536u]);
        v7 = __builtin_nontemporal_load(&x4[base + 1792u]);
    }

    // ---- (2) per-wave table build (lane 0 of each wave); no barriers — each
    //          wave reads only its own slot, ordered by its own lgkmcnt ----
    float* tab = s_tab[threadIdx.x >> 6];
    if ((threadIdx.x & 63) == 0) {
        // softmax(theta), fp32, sequential order (bit-matched all rounds)
        float mx = th[0];
        #pragma unroll
        for (int i = 1; i < KB; ++i) mx = fmaxf(mx, th[i]);
        float ex[KB];
        float sum = 0.0f;
        #pragma unroll
        for (int i = 0; i < KB; ++i) { ex[i] = expf(__fsub_rn(th[i], mx)); sum = __fadd_rn(sum, ex[i]); }
        float sm[KB];
        #pragma unroll
        for (int i = 0; i < KB; ++i) sm[i] = __fdiv_rn(ex[i], sum);

        float beta[KB], gamma[KB];
        beta[0] = 0.0f;
        float c = sm[0];
        #pragma unroll
        for (int i = 1; i < KB; ++i) { beta[i] = c; c = __fadd_rn(c, sm[i]); }
        #pragma unroll
        for (int i = 0; i < KB; ++i) gamma[i] = __fmul_rn(sm[i], 16.0f);

        // gamma16 = gamma/16 — exact pow2 scale (== sm[i] bitwise)
        #pragma unroll
        for (int i = 0; i < KB; ++i)
            ((float2*)tab)[i] = make_float2(__fmul_rn(gamma[i], 0.0625f), beta[i]);

        // pv[m] = alpha * expand(m/15): searchsorted + inverse affine (uses
        // REAL gamma), then the reference's alpha-multiply pre-folded
        for (int m = 0; m < KB; ++m) {
            float yq = __fdiv_rn((float)m, 15.0f);
            int iq = 0;
            #pragma unroll
            for (int i = 1; i < KB; ++i) iq += (beta[i] <= yq) ? 1 : 0;
            float zv = __fadd_rn(__fdiv_rn(__fsub_rn(yq, beta[iq]), gamma[iq]),
                                 (float)iq * 0.0625f);
            tab[32 + m] = __fmul_rn(alpha, zv);
        }
    }
    const float2* gbp = (const float2*)tab;
    const float*  pvp = tab + 32;

#define LCQ_CS(V, off) { \
        vf4 r; \
        r.x = lcq_core(V.x, alpha, rcpa16, gbp, pvp); \
        r.y = lcq_core(V.y, alpha, rcpa16, gbp, pvp); \
        r.z = lcq_core(V.z, alpha, rcpa16, gbp, pvp); \
        r.w = lcq_core(V.w, alpha, rcpa16, gbp, pvp); \
        __builtin_nontemporal_store(r, &o4[base + (off)]); }

    // ---- (3) iteration 1: per-chunk compute + NT store ----
    if (full0) {
        LCQ_CS(v0, 0u)
        LCQ_CS(v1, 256u)
        LCQ_CS(v2, 512u)
        LCQ_CS(v3, 768u)
        LCQ_CS(v4, 1024u)
        LCQ_CS(v5, 1280u)
        LCQ_CS(v6, 1536u)
        LCQ_CS(v7, 1792u)
    }

    // ---- (4) iteration 2: reuse the SAME 8 registers (stays in the <=64
    //          VGPR tier); loads issue behind iter-1 stores, fire-and-forget ----
    const bool full1 = ((long long)blockIdx.x * 4096ll + 4096ll <= n4ll);
    if (full1) {
        v0 = __builtin_nontemporal_load(&x4[base + 2048u]);
        v1 = __builtin_nontemporal_load(&x4[base + 2304u]);
        v2 = __builtin_nontemporal_load(&x4[base + 2560u]);
        v3 = __builtin_nontemporal_load(&x4[base + 2816u]);
        v4 = __builtin_nontemporal_load(&x4[base + 3072u]);
        v5 = __builtin_nontemporal_load(&x4[base + 3328u]);
        v6 = __builtin_nontemporal_load(&x4[base + 3584u]);
        v7 = __builtin_nontemporal_load(&x4[base + 3840u]);
        LCQ_CS(v0, 2048u)
        LCQ_CS(v1, 2304u)
        LCQ_CS(v2, 2560u)
        LCQ_CS(v3, 2816u)
        LCQ_CS(v4, 3072u)
        LCQ_CS(v5, 3328u)
        LCQ_CS(v6, 3584u)
        LCQ_CS(v7, 3840u)
    }
#undef LCQ_CS

    // ---- (5) partial coverage (not hit at bench shape; kept for generality) ----
    if (!full0 || !full1) {
        const int k0 = full0 ? 8 : 0;   // chunks already done
        #pragma unroll 1
        for (int k = k0; k < 16; ++k) {
            long long i = (long long)base + (long long)k * 256;
            if (i < n4ll) {
                vf4 v = x4[i];
                vf4 r;
                r.x = lcq_core(v.x, alpha, rcpa16, gbp, pvp);
                r.y = lcq_core(v.y, alpha, rcpa16, gbp, pvp);
                r.z = lcq_core(v.z, alpha, rcpa16, gbp, pvp);
                r.w = lcq_core(v.w, alpha, rcpa16, gbp, pvp);
                o4[i] = r;
            }
        }
        // scalar remainder (n % 4), handled by the last block only
        if (blockIdx.x == gridDim.x - 1) {
            for (long long k = (n4ll << 2) + threadIdx.x; k < n; k += 256) {
                out[k] = lcq_core(x[k], alpha, rcpa16, gbp, pvp);
            }
        }
    }
}

extern "C" void kernel_launch(void* const* d_in, const int* in_sizes, int n_in,
                              void* d_out, int out_size, void* d_ws, size_t ws_size,
                              hipStream_t stream) {
    const float* x     = (const float*)d_in[0];   // (4,4096,2048) fp32
    const float* thr   = (const float*)d_in[1];   // (1,) alpha
    const float* theta = (const float*)d_in[2];   // (16,)
    float* out = (float*)d_out;

    long long n = (long long)in_sizes[0];
    long long n4 = n >> 2;
    long long grid = (n4 + 4095) / 4096;          // bench: 2048 blocks x 2 iters
    if (grid < 1) grid = 1;
    dim3 block(256);
    hipLaunchKernelGGL(lcq_kernel, dim3((unsigned)grid), block, 0, stream,
                       x, thr, theta, out, n);
}